// Round 6
// baseline (134.357 us; speedup 1.0000x reference)
//
#include <hip/hip_runtime.h>
#include <math.h>

// TopKMoEGate: T = 16384, D = 1024, E = 64, topK = 2.
// Round 6: barrier-free MFMA path. 3-slice bf16 split (verified r4/r5).
//  - r5 lesson: per-chunk global_load_lds + __syncthreads drains vmcnt(0)
//    collectively -> stalls all 16 waves; and NSPLIT=4 = single block
//    generation per CU (no pipelining, full tail).
//  - Fix: NO LDS, NO barriers. B-frags load directly from the pre-permuted
//    wimg (r5's LDS-lane-order image): lane-consecutive 16B units ->
//    perfectly coalesced 1KB/instr, L1-hot across the block's 4 waves.
//    Each wave's B latency is hidden by other waves' MFMAs (16 waves/CU).
//  - NSPLIT=8: 2048 blocks = 2 generations of 4 blocks/CU.
//  - reduce_topk (r3-verified butterfly) sums 8 partials + noise + top-2
//    + sparse softmax.

#define DDIM 1024
#define NEXP 64
#define NTOK 16384
#define NSPLIT 8
#define CPB 2                 // k64-chunks per block (K range 128)

typedef float f4 __attribute__((ext_vector_type(4)));
typedef short s8 __attribute__((ext_vector_type(8)));
typedef unsigned int u32;

static __device__ __forceinline__ void split3(float f, short& h, short& m, short& l) {
    const u32 uf = __float_as_uint(f);
    h = (short)(uf >> 16);
    const float r1 = f - __uint_as_float(uf & 0xffff0000u);
    const u32 u1 = __float_as_uint(r1);
    m = (short)(u1 >> 16);
    const float r2 = r1 - __uint_as_float(u1 & 0xffff0000u);
    l = (short)(__float_as_uint(r2) >> 16);
}

// ---- kernel 0: slice gate_w into 3 bf16 levels, lane-ordered image ----
// unit16 U(c,kk,lv,t,q,m) = c*1536 + (kk*3+lv)*256 + t*64 + q*16 + m,
// holding w[e=t*16+m][k0..k0+7], k0 = c*64 + kk*32 + q*8.  (r5-verified)
__global__ __launch_bounds__(256)
void w_prep(const float* __restrict__ gw, short* __restrict__ wimg) {
    const int uid = blockIdx.x * 256 + threadIdx.x;   // 8192 threads
    const int c   = uid >> 9;
    const int kk  = (uid >> 8) & 1;
    const int e   = (uid >> 2) & 63;
    const int q   = uid & 3;
    const int k0  = c * 64 + kk * 32 + q * 8;
    const float* src = gw + (size_t)e * DDIM + k0;
    s8 hv, mv, lv;
    #pragma unroll
    for (int j = 0; j < 8; ++j) {
        short h, m, l;
        split3(src[j], h, m, l);
        hv[j] = h; mv[j] = m; lv[j] = l;
    }
    const size_t base = (size_t)c * 1536 + (kk * 3) * 256
                      + (e >> 4) * 64 + q * 16 + (e & 15);
    *(s8*)(wimg + (base      ) * 8) = hv;
    *(s8*)(wimg + (base + 256) * 8) = mv;
    *(s8*)(wimg + (base + 512) * 8) = lv;
}

// ---- kernel 1: split-K MFMA GEMM -> fp32 partials (no LDS, no barriers) ----
__global__ __launch_bounds__(256, 4)
void gemm_partial(const float* __restrict__ x,
                  const short* __restrict__ wimg,
                  float* __restrict__ part)     // [NSPLIT][NTOK][NEXP]
{
    const int tid   = threadIdx.x;
    const int lane  = tid & 63;
    const int wv    = tid >> 6;
    const int m     = lane & 15;                // token row / frag index
    const int q     = lane >> 4;                // k-octet quad
    const int tile  = blockIdx.x & 255;
    const int split = blockIdx.x >> 8;
    const int tokBase = tile * 64 + wv * 16;

    const float* xrow = x + (size_t)(tokBase + m) * DDIM
                      + split * (CPB * 64) + q * 8;

    f4 acc0[4], acc1[4];
    #pragma unroll
    for (int t = 0; t < 4; ++t) { acc0[t] = (f4)0.f; acc1[t] = (f4)0.f; }

    // A fp32 staging, depth-1 prefetch
    f4 stage[2][4];
    stage[0][0] = *(const f4*)(xrow);
    stage[0][1] = *(const f4*)(xrow + 4);
    stage[0][2] = *(const f4*)(xrow + 32);
    stage[0][3] = *(const f4*)(xrow + 36);

    #pragma unroll
    for (int cc = 0; cc < CPB; ++cc) {
        if (cc + 1 < CPB) {
            const float* s = xrow + (cc + 1) * 64;
            stage[(cc + 1) & 1][0] = *(const f4*)(s);
            stage[(cc + 1) & 1][1] = *(const f4*)(s + 4);
            stage[(cc + 1) & 1][2] = *(const f4*)(s + 32);
            stage[(cc + 1) & 1][3] = *(const f4*)(s + 36);
        }

        // convert current A chunk -> 3-level bf16 frags
        s8 ah[2], am[2], al[2];
        const float* sv = (const float*)stage[cc & 1];
        #pragma unroll
        for (int kk = 0; kk < 2; ++kk)
            #pragma unroll
            for (int j = 0; j < 8; ++j) {
                short h, mm, l;
                split3(sv[kk * 8 + j], h, mm, l);
                ah[kk][j] = h; am[kk][j] = mm; al[kk][j] = l;
            }

        // B direct from global: lane-consecutive units -> coalesced 1KB/instr
        const short* cb = wimg + (size_t)(split * CPB + cc) * (1536 * 8);
        #pragma unroll
        for (int kk = 0; kk < 2; ++kk) {
            #pragma unroll
            for (int t = 0; t < 4; ++t) {
                const int pb = (kk * 3) * 256 + t * 64 + lane;
                const s8 bh = *(const s8*)(cb + (size_t)(pb      ) * 8);
                const s8 bm = *(const s8*)(cb + (size_t)(pb + 256) * 8);
                const s8 bl = *(const s8*)(cb + (size_t)(pb + 512) * 8);
                acc0[t] = __builtin_amdgcn_mfma_f32_16x16x32_bf16(ah[kk], bh, acc0[t], 0, 0, 0);
                acc1[t] = __builtin_amdgcn_mfma_f32_16x16x32_bf16(ah[kk], bm, acc1[t], 0, 0, 0);
                acc1[t] = __builtin_amdgcn_mfma_f32_16x16x32_bf16(am[kk], bh, acc1[t], 0, 0, 0);
                acc1[t] = __builtin_amdgcn_mfma_f32_16x16x32_bf16(ah[kk], bl, acc1[t], 0, 0, 0);
                acc1[t] = __builtin_amdgcn_mfma_f32_16x16x32_bf16(am[kk], bm, acc1[t], 0, 0, 0);
                acc1[t] = __builtin_amdgcn_mfma_f32_16x16x32_bf16(al[kk], bh, acc1[t], 0, 0, 0);
            }
        }
    }

    // store partials: C row = q*4+r (token), col = m (+16t experts)
    #pragma unroll
    for (int t = 0; t < 4; ++t)
        #pragma unroll
        for (int r = 0; r < 4; ++r)
            part[((size_t)split * NTOK + tokBase + q * 4 + r) * NEXP + m + 16 * t]
                = acc0[t][r] + acc1[t][r];
}

// ---- kernel 2: reduce splits + noisy top-2 + sparse softmax (r3-verified) ----
__global__ __launch_bounds__(256)
void reduce_topk(const float* __restrict__ part,
                 const float* __restrict__ noise_weight,
                 const float* __restrict__ noise,
                 float* __restrict__ out_w,
                 float* __restrict__ out_i)
{
    const int lane  = threadIdx.x & 63;          // expert
    const int wv    = threadIdx.x >> 6;
    const int token = blockIdx.x * 4 + wv;

    float sum = 0.f;
    #pragma unroll
    for (int s = 0; s < NSPLIT; ++s)
        sum += part[((size_t)s * NTOK + token) * NEXP + lane];

    const float ln = fmaf(noise[(size_t)token * NEXP + lane], noise_weight[lane], sum);

    float v1 = ln; int i1 = lane;
    #pragma unroll
    for (int off = 32; off > 0; off >>= 1) {
        const float vo = __shfl_xor(v1, off, 64);
        const int   io = __shfl_xor(i1, off, 64);
        if (vo > v1 || (vo == v1 && io < i1)) { v1 = vo; i1 = io; }
    }
    float v2 = (lane == i1) ? -3.4e38f : ln; int i2 = lane;
    #pragma unroll
    for (int off = 32; off > 0; off >>= 1) {
        const float vo = __shfl_xor(v2, off, 64);
        const int   io = __shfl_xor(i2, off, 64);
        if (vo > v2 || (vo == v2 && io < i2)) { v2 = vo; i2 = io; }
    }

    const float d   = expf(v2 - v1);
    const float inv = 1.f / (1.f + d);
    const float wgt = (lane == i1) ? inv : ((lane == i2) ? d * inv : 0.f);
    out_w[(size_t)token * NEXP + lane] = wgt;
    if (lane == 0) {
        out_i[(size_t)token * 2]     = (float)i1;
        out_i[(size_t)token * 2 + 1] = (float)i2;
    }
}

extern "C" void kernel_launch(void* const* d_in, const int* in_sizes, int n_in,
                              void* d_out, int out_size, void* d_ws, size_t ws_size,
                              hipStream_t stream) {
    const float* x     = (const float*)d_in[0];
    const float* gw    = (const float*)d_in[1];
    const float* nwt   = (const float*)d_in[2];
    const float* noise = (const float*)d_in[3];
    float* out_w = (float*)d_out;                        // [NTOK][64]
    float* out_i = (float*)d_out + (size_t)NTOK * NEXP;  // [NTOK][2] as float

    short* wimg = (short*)d_ws;                          // 384 KB image
    float* part = (float*)((char*)d_ws + 512 * 1024);    // 32 MB partials

    hipLaunchKernelGGL(w_prep, dim3(32), dim3(256), 0, stream, gw, wimg);
    hipLaunchKernelGGL(gemm_partial, dim3(256 * NSPLIT), dim3(256), 0, stream,
                       x, wimg, part);
    hipLaunchKernelGGL(reduce_topk, dim3(NTOK / 4), dim3(256), 0, stream,
                       part, nwt, noise, out_w, out_i);
}

// Round 7
// 124.862 us; speedup vs baseline: 1.0760x; 1.0760x over previous
//
#include <hip/hip_runtime.h>
#include <math.h>

// TopKMoEGate: T = 16384, D = 1024, E = 64, topK = 2.
// Round 7: stage-B-once MFMA path. 3-slice bf16 split (r4/r5/r6-verified).
//  - r5 lesson: per-chunk global_load_lds + barrier -> repeated vmcnt(0)
//    drains (gemm ~30 us). r6 lesson: B from global = 48 serial 200-cyc
//    L2 load->MFMA chains per wave, latency-bound (gemm 44 us).
//  - Fix: stage the block's whole B-slice (48 KB, pre-permuted lane order)
//    into LDS ONCE via global_load_lds w=16, ONE barrier, then a fully
//    barrier-free K-loop: B via ds_read_b128 (~12 cyc, 2-way alias = free),
//    A pre-loaded up-front (8 f4 loads in flight -> single HBM exposure).
//  - NSPLIT=8 (2048 blocks), LDS 48 KB -> 3 blocks/CU, 12 waves/CU.
//  - reduce_topk (r3-verified butterfly): sum 8 partials + noise + top-2
//    + sparse softmax.

#define DDIM 1024
#define NEXP 64
#define NTOK 16384
#define NSPLIT 8
#define CPB 2                 // k64-chunks per block (K range 128)
#define CHUNK_SH 12288        // shorts per k64 chunk (1536 units * 8)

typedef float f4 __attribute__((ext_vector_type(4)));
typedef short s8 __attribute__((ext_vector_type(8)));
typedef unsigned int u32;

static __device__ __forceinline__ void split3(float f, short& h, short& m, short& l) {
    const u32 uf = __float_as_uint(f);
    h = (short)(uf >> 16);
    const float r1 = f - __uint_as_float(uf & 0xffff0000u);
    const u32 u1 = __float_as_uint(r1);
    m = (short)(u1 >> 16);
    const float r2 = r1 - __uint_as_float(u1 & 0xffff0000u);
    l = (short)(__float_as_uint(r2) >> 16);
}

static __device__ __forceinline__ void gl_lds16(const void* g, void* l) {
    __builtin_amdgcn_global_load_lds(
        (const __attribute__((address_space(1))) u32*)g,
        (__attribute__((address_space(3))) u32*)l, 16, 0, 0);
}

// ---- kernel 0: slice gate_w into 3 bf16 levels, lane-ordered image ----
// unit16 U(c,kk,lv,t,q,m) = c*1536 + (kk*3+lv)*256 + t*64 + q*16 + m,
// holding w[e=t*16+m][k0..k0+7], k0 = c*64 + kk*32 + q*8.  (r5-verified)
__global__ __launch_bounds__(256)
void w_prep(const float* __restrict__ gw, short* __restrict__ wimg) {
    const int uid = blockIdx.x * 256 + threadIdx.x;   // 8192 threads
    const int c   = uid >> 9;
    const int kk  = (uid >> 8) & 1;
    const int e   = (uid >> 2) & 63;
    const int q   = uid & 3;
    const int k0  = c * 64 + kk * 32 + q * 8;
    const float* src = gw + (size_t)e * DDIM + k0;
    s8 hv, mv, lv;
    #pragma unroll
    for (int j = 0; j < 8; ++j) {
        short h, m, l;
        split3(src[j], h, m, l);
        hv[j] = h; mv[j] = m; lv[j] = l;
    }
    const size_t base = (size_t)c * 1536 + (kk * 3) * 256
                      + (e >> 4) * 64 + q * 16 + (e & 15);
    *(s8*)(wimg + (base      ) * 8) = hv;
    *(s8*)(wimg + (base + 256) * 8) = mv;
    *(s8*)(wimg + (base + 512) * 8) = lv;
}

// ---- kernel 1: split-K MFMA GEMM -> fp32 partials (one barrier total) ----
__global__ __launch_bounds__(256, 3)
void gemm_partial(const float* __restrict__ x,
                  const short* __restrict__ wimg,
                  float* __restrict__ part)     // [NSPLIT][NTOK][NEXP]
{
    __shared__ short bs[CPB * CHUNK_SH];        // 48 KB: whole B-slice

    const int tid   = threadIdx.x;
    const int lane  = tid & 63;
    const int wv    = tid >> 6;
    const int m     = lane & 15;                // token row / frag index
    const int q     = lane >> 4;                // k-octet quad
    const int tile  = blockIdx.x & 255;
    const int split = blockIdx.x >> 8;
    const int tokBase = tile * 64 + wv * 16;

    // issue B staging first (async, direct-to-LDS), then A loads: all in
    // flight together, one latency exposure, ONE barrier.
    const short* bsrc = wimg + (size_t)(split * CPB) * CHUNK_SH;
    #pragma unroll
    for (int i = 0; i < 12; ++i) {              // 4 waves x 12 KB = 48 KB
        const int off = (wv * 12 + i) * 512;    // shorts (1 KB per wave-iter)
        gl_lds16(bsrc + off + lane * 8, &bs[off]);
    }

    const float* xrow = x + (size_t)(tokBase + m) * DDIM
                      + split * (CPB * 64) + q * 8;
    f4 A[8];
    #pragma unroll
    for (int cc = 0; cc < CPB; ++cc) {
        A[cc * 4 + 0] = *(const f4*)(xrow + cc * 64);
        A[cc * 4 + 1] = *(const f4*)(xrow + cc * 64 + 4);
        A[cc * 4 + 2] = *(const f4*)(xrow + cc * 64 + 32);
        A[cc * 4 + 3] = *(const f4*)(xrow + cc * 64 + 36);
    }

    f4 acc0[4], acc1[4];
    #pragma unroll
    for (int t = 0; t < 4; ++t) { acc0[t] = (f4)0.f; acc1[t] = (f4)0.f; }

    __syncthreads();                            // B visible; A already in regs

    #pragma unroll
    for (int cc = 0; cc < CPB; ++cc) {
        // convert this chunk's 16 fp32 -> 3-level bf16 A-frags
        s8 ah[2], am[2], al[2];
        const float* sv = (const float*)&A[cc * 4];
        #pragma unroll
        for (int kk = 0; kk < 2; ++kk)
            #pragma unroll
            for (int j = 0; j < 8; ++j) {
                short h, mm, l;
                split3(sv[kk * 8 + j], h, mm, l);
                ah[kk][j] = h; am[kk][j] = mm; al[kk][j] = l;
            }

        #pragma unroll
        for (int kk = 0; kk < 2; ++kk) {
            #pragma unroll
            for (int t = 0; t < 4; ++t) {
                const int pb = cc * 1536 + (kk * 3) * 256 + t * 64 + lane;
                const s8 bh = *(const s8*)&bs[(size_t)(pb      ) * 8];
                const s8 bm = *(const s8*)&bs[(size_t)(pb + 256) * 8];
                const s8 bl = *(const s8*)&bs[(size_t)(pb + 512) * 8];
                acc0[t] = __builtin_amdgcn_mfma_f32_16x16x32_bf16(ah[kk], bh, acc0[t], 0, 0, 0);
                acc1[t] = __builtin_amdgcn_mfma_f32_16x16x32_bf16(ah[kk], bm, acc1[t], 0, 0, 0);
                acc1[t] = __builtin_amdgcn_mfma_f32_16x16x32_bf16(am[kk], bh, acc1[t], 0, 0, 0);
                acc1[t] = __builtin_amdgcn_mfma_f32_16x16x32_bf16(ah[kk], bl, acc1[t], 0, 0, 0);
                acc1[t] = __builtin_amdgcn_mfma_f32_16x16x32_bf16(am[kk], bm, acc1[t], 0, 0, 0);
                acc1[t] = __builtin_amdgcn_mfma_f32_16x16x32_bf16(al[kk], bh, acc1[t], 0, 0, 0);
            }
        }
    }

    // store partials: C row = q*4+r (token), col = m (+16t experts)
    #pragma unroll
    for (int t = 0; t < 4; ++t)
        #pragma unroll
        for (int r = 0; r < 4; ++r)
            part[((size_t)split * NTOK + tokBase + q * 4 + r) * NEXP + m + 16 * t]
                = acc0[t][r] + acc1[t][r];
}

// ---- kernel 2: reduce splits + noisy top-2 + sparse softmax (r3-verified) ----
__global__ __launch_bounds__(256)
void reduce_topk(const float* __restrict__ part,
                 const float* __restrict__ noise_weight,
                 const float* __restrict__ noise,
                 float* __restrict__ out_w,
                 float* __restrict__ out_i)
{
    const int lane  = threadIdx.x & 63;          // expert
    const int wv    = threadIdx.x >> 6;
    const int token = blockIdx.x * 4 + wv;

    float sum = 0.f;
    #pragma unroll
    for (int s = 0; s < NSPLIT; ++s)
        sum += part[((size_t)s * NTOK + token) * NEXP + lane];

    const float ln = fmaf(noise[(size_t)token * NEXP + lane], noise_weight[lane], sum);

    float v1 = ln; int i1 = lane;
    #pragma unroll
    for (int off = 32; off > 0; off >>= 1) {
        const float vo = __shfl_xor(v1, off, 64);
        const int   io = __shfl_xor(i1, off, 64);
        if (vo > v1 || (vo == v1 && io < i1)) { v1 = vo; i1 = io; }
    }
    float v2 = (lane == i1) ? -3.4e38f : ln; int i2 = lane;
    #pragma unroll
    for (int off = 32; off > 0; off >>= 1) {
        const float vo = __shfl_xor(v2, off, 64);
        const int   io = __shfl_xor(i2, off, 64);
        if (vo > v2 || (vo == v2 && io < i2)) { v2 = vo; i2 = io; }
    }

    const float d   = expf(v2 - v1);
    const float inv = 1.f / (1.f + d);
    const float wgt = (lane == i1) ? inv : ((lane == i2) ? d * inv : 0.f);
    out_w[(size_t)token * NEXP + lane] = wgt;
    if (lane == 0) {
        out_i[(size_t)token * 2]     = (float)i1;
        out_i[(size_t)token * 2 + 1] = (float)i2;
    }
}

extern "C" void kernel_launch(void* const* d_in, const int* in_sizes, int n_in,
                              void* d_out, int out_size, void* d_ws, size_t ws_size,
                              hipStream_t stream) {
    const float* x     = (const float*)d_in[0];
    const float* gw    = (const float*)d_in[1];
    const float* nwt   = (const float*)d_in[2];
    const float* noise = (const float*)d_in[3];
    float* out_w = (float*)d_out;                        // [NTOK][64]
    float* out_i = (float*)d_out + (size_t)NTOK * NEXP;  // [NTOK][2] as float

    short* wimg = (short*)d_ws;                          // 384 KB image
    float* part = (float*)((char*)d_ws + 512 * 1024);    // 32 MB partials

    hipLaunchKernelGGL(w_prep, dim3(32), dim3(256), 0, stream, gw, wimg);
    hipLaunchKernelGGL(gemm_partial, dim3(256 * NSPLIT), dim3(256), 0, stream,
                       x, wimg, part);
    hipLaunchKernelGGL(reduce_topk, dim3(NTOK / 4), dim3(256), 0, stream,
                       part, nwt, noise, out_w, out_i);
}